// Round 12
// baseline (254.204 us; speedup 1.0000x reference)
//
#include <hip/hip_runtime.h>
#include <hip/hip_bf16.h>

#define D 128
#define LOG2E 1.4426950408889634f

typedef __attribute__((ext_vector_type(8))) short bf16x8;
typedef __attribute__((ext_vector_type(4))) float f32x4;
typedef __attribute__((ext_vector_type(2))) float f32x2;
typedef __attribute__((ext_vector_type(2))) unsigned u32x2;
typedef __attribute__((ext_vector_type(4))) unsigned u32x4;

__device__ __forceinline__ unsigned short f2bf_bits(float f) {
    union { __hip_bfloat16 h; unsigned short u; } c;
    c.h = __float2bfloat16(f);
    return c.u;
}
__device__ __forceinline__ float bfbits2f(unsigned short u) {
    return __uint_as_float(((unsigned)u) << 16);
}
__device__ __forceinline__ float ldf(const void* p, size_t i, int f32) {
    return f32 ? ((const float*)p)[i] : bfbits2f(((const unsigned short*)p)[i]);
}
// word -> (lo bf16, hi bf16) as packed f32 pair
__device__ __forceinline__ f32x2 unpk2(unsigned u) {
    f32x2 r;
    r.x = __uint_as_float(u << 16);
    r.y = __uint_as_float(u & 0xFFFF0000u);
    return r;
}
__device__ __forceinline__ f32x2 shx32(f32x2 v) {
    f32x2 r;
    r.x = __shfl_xor(v.x, 32);
    r.y = __shfl_xor(v.y, 32);
    return r;
}
// Forced packed-fp32 math (backend does not reliably select these from IR)
__device__ __forceinline__ f32x2 pk_add(f32x2 a, f32x2 b) {
    f32x2 d;
    asm("v_pk_add_f32 %0, %1, %2" : "=v"(d) : "v"(a), "v"(b));
    return d;
}
__device__ __forceinline__ f32x2 pk_mul(f32x2 a, f32x2 b) {
    f32x2 d;
    asm("v_pk_mul_f32 %0, %1, %2" : "=v"(d) : "v"(a), "v"(b));
    return d;
}
__device__ __forceinline__ f32x2 pk_fma(f32x2 a, f32x2 b, f32x2 c) {
    f32x2 d;
    asm("v_pk_fma_f32 %0, %1, %2, %3" : "=v"(d) : "v"(a), "v"(b), "v"(c));
    return d;
}
__device__ __forceinline__ float fexp2(float x) {  // raw v_exp_f32 (2^x)
    float r;
    asm("v_exp_f32 %0, %1" : "=v"(r) : "v"(x));
    return r;
}

// Fragment-major W layout: 16B-unit index for element (row, k):
//   f16 = ((row>>4)*4 + (k>>5))*64 + ((k>>3)&3)*16 + (row&15)
__device__ __forceinline__ size_t fragIdx(int row, int k) {
    int f16 = ((row >> 4) * 4 + (k >> 5)) * 64 + ((k >> 3) & 3) * 16 + (row & 15);
    return (size_t)f16 * 8 + (k & 7);
}

// Software grid barrier over the first nblk blocks (all co-resident:
// grid 468 blocks x 256 thr << 2048-block capacity). Device-scope atomics.
__device__ __forceinline__ void gridbar(int* bar, int idx, int nblk) {
    __syncthreads();
    if (threadIdx.x == 0) {
        __threadfence();
        atomicAdd(&bar[idx], 1);
        while (atomicAdd(&bar[idx], 0) < nblk)
            __builtin_amdgcn_s_sleep(2);
        __threadfence();
    }
    __syncthreads();
}

// ---- K1 (FUSED): blocks [0,nbScan): zero cnt -> bar -> count+rank -> bar
//      -> local scan -> publish -> bar -> carry + offs   (replaces the old
//      memset(cnt) + count range + scan_block + scan_fix: 3 fewer dispatches;
//      runs concurrently with the weight blocks).
//      blocks [nbScan, nbScan+272): weight prep (dtype-detect + wq matmul +
//      5 transposes), all tables stored FRAGMENT-MAJOR.
// Cross-block data inside this kernel (cnt, part, bar) is accessed ONLY via
// device-scope atomics (atomicExch write / atomicAdd(p,0) read) to avoid
// stale per-XCD L2 / per-CU L1 lines. rank/offs are plain stores read only
// by later dispatches.
__global__ __launch_bounds__(256) void prep_kernel(
    const void* __restrict__ node, const void* __restrict__ wtrip,
    const void* __restrict__ wquad, const void* __restrict__ loopW,
    const void* __restrict__ evoW, unsigned short* __restrict__ wT,
    int* __restrict__ cnt, int* __restrict__ offs, int* __restrict__ part,
    int* __restrict__ rank, const int* __restrict__ dst,
    int* __restrict__ flag, int* __restrict__ bar, int E, int N, int nbScan) {
    int tid = threadIdx.x;
    int bx = blockIdx.x;

    if (bx < nbScan) {
        __shared__ int sh[256];
        int i0 = bx * 256 + tid;
        // phase 0: zero cnt (atomic store -> visible at device coherence point)
        if (i0 < N) atomicExch(&cnt[i0], 0);
        gridbar(bar, 0, nbScan);
        // phase 1: count + rank (device-scope atomics; ~13 edges/thread)
        for (int e = bx * 256 + tid; e < E; e += nbScan * 256)
            rank[e] = atomicAdd(&cnt[dst[e]], 1);
        gridbar(bar, 1, nbScan);
        // phase 2: block-local inclusive scan of this block's 256-entry slice
        int v = (i0 < N) ? atomicAdd(&cnt[i0], 0) : 0;
        sh[tid] = v;
        __syncthreads();
        for (int o = 1; o < 256; o <<= 1) {
            int t = (tid >= o) ? sh[tid - o] : 0;
            __syncthreads();
            sh[tid] += t;
            __syncthreads();
        }
        int myexcl = sh[tid] - v;
        if (tid == 255) atomicExch(&part[bx], sh[255]);
        gridbar(bar, 2, nbScan);
        // phase 3: carry = sum part[0..bx) (nbScan <= 256), write offs
        sh[tid] = (tid < bx) ? atomicAdd(&part[tid], 0) : 0;
        __syncthreads();
        for (int o = 128; o; o >>= 1) {
            if (tid < o) sh[tid] += sh[tid + o];
            __syncthreads();
        }
        int carry = sh[0];
        if (i0 < N) offs[i0] = myexcl + carry;
        if (bx == 0 && tid == 0) offs[N] = E;
        return;
    }

    // ---- weight blocks ----
    int wbx = bx - nbScan;  // [0, 272)
    __shared__ int sflag;
    int bad = 0;
    if (tid < 64) {
        for (int j = 0; j < 4; j++) {
            float v = bfbits2f(((const unsigned short*)node)[tid + 64 * j]);
            if (!(fabsf(v) < 1e4f)) bad = 1;
        }
    }
    unsigned long long m = __ballot(bad);
    if (tid == 0) sflag = (m != 0ull) ? 1 : 0;
    __syncthreads();
    int f32 = sflag;
    if (wbx == 0 && tid == 0) *flag = f32;

    if (wbx < 192) {
        int unit = wbx * 2 + (tid >> 7);
        int k = unit & 127, mjob = unit >> 7;
        int t = tid & 127;
        float acc = 0.f;
        for (int j = 0; j < D; j++)
            acc += ldf(wtrip, (size_t)mjob * D * D + (size_t)k * D + j, f32) *
                   ldf(wquad, (size_t)j * D + t, f32);
        const int jmap0 = (mjob == 0) ? 0 : (mjob == 1 ? 6 : 2);
        wT[(size_t)jmap0 * D * D + fragIdx(t, k)] = f2bf_bits(acc);
    } else {
        int u = wbx - 192;  // [0,80): 5 jobs x 16 segments
        int jr = u >> 4, seg = u & 15;
        const void* srcp; size_t base; int j;
        switch (jr) {
            case 0: srcp = wtrip; base = 0;             j = 1; break;
            case 1: srcp = wtrip; base = 2 * D * D;     j = 3; break;
            case 2: srcp = loopW; base = 0;             j = 4; break;
            case 3: srcp = evoW;  base = 0;             j = 5; break;
            default: srcp = wtrip; base = (size_t)D * D; j = 7; break;
        }
        for (int c = tid; c < 1024; c += 256) {
            int idx = seg * 1024 + c;
            int n = idx >> 7, k = idx & 127;
            unsigned short b = f32 ? f2bf_bits(((const float*)srcp)[base + (size_t)k * D + n])
                                   : ((const unsigned short*)srcp)[base + (size_t)k * D + n];
            wT[(size_t)j * D * D + fragIdx(n, k)] = b;
        }
    }
}

// ---- K4: table GEMM, R11 best (225.6us): single barrier, both W tables
// (64KB, fragment-major) staged up-front with 8 coalesced loads in flight,
// then 64 MFMA uninterrupted. Scatter fused at y==1 x-overflow.
__global__ __launch_bounds__(512) void gemm_kernel(
    const void* __restrict__ node, const void* __restrict__ rel,
    const unsigned short* __restrict__ wT, const int* __restrict__ cnt,
    unsigned* __restrict__ nodeST, unsigned* __restrict__ nodeDT,
    unsigned* __restrict__ relRT, unsigned* __restrict__ loopSel,
    const int* __restrict__ flag, int N, int R, int nodeBlocks,
    const int* __restrict__ src, const int* __restrict__ dst,
    const int* __restrict__ et, const int* __restrict__ offs,
    const int* __restrict__ rank, u32x2* __restrict__ ePack, int E) {
    __shared__ __align__(16) unsigned short Wt[2][D * D];

    int bx = blockIdx.x, by = blockIdx.y;
    int tid = threadIdx.y * 64 + threadIdx.x;
    int isRel = 0, jp;
    if (bx >= nodeBlocks) {
        if (by == 1) {  // scatter range: pure (no atomics)
            int e = (bx - nodeBlocks) * 512 + tid;
            if (e < E) {
                int d = dst[e];
                u32x2 pk;
                pk.x = ((unsigned)src[e]) << 9;
                pk.y = ((unsigned)et[e]) << 9;
                ePack[offs[d] + rank[e]] = pk;
            }
            return;
        }
        if (by != 0 || bx - nodeBlocks >= (R + 127) / 128) return;
        isRel = 1;
        jp = 3;
    } else {
        jp = by;
    }

    int f32 = *flag;
    int rows = isRel ? R : N;
    int row0 = (isRel ? bx - nodeBlocks : bx) * 128;
    const void* A = isRel ? rel : node;

    int lane = threadIdx.x, wv = threadIdx.y;  // wv in [0,8)
    int l16 = lane & 15, quad = lane >> 4;
    int ar = row0 + wv * 16 + l16;
    int ar_c = ar < rows ? ar : rows - 1;

    int qIdx, tIdx;
    unsigned* O = nullptr;
    switch (jp) {
        case 0: qIdx = 0; tIdx = 1; O = nodeST; break;
        case 1: qIdx = 2; tIdx = 3; O = nodeDT; break;
        case 2: qIdx = 4; tIdx = 5; break;  // loopW/evoW pair
        default: qIdx = 6; tIdx = 7; O = relRT; break;
    }

    const unsigned short* gQ = wT + (size_t)qIdx * D * D;
    const unsigned short* gT = wT + (size_t)tIdx * D * D;

    bf16x8 wq[4], wt[4];
#pragma unroll
    for (int i = 0; i < 4; i++)
        wq[i] = *(const bf16x8*)(gQ + (size_t)(tid + i * 512) * 8);
#pragma unroll
    for (int i = 0; i < 4; i++)
        wt[i] = *(const bf16x8*)(gT + (size_t)(tid + i * 512) * 8);

    bf16x8 af[4];
#pragma unroll
    for (int kk = 0; kk < 4; kk++) {
        int k = kk * 32 + quad * 8;
        if (f32) {
            const float* Af = (const float*)A + (size_t)ar_c * D + k;
            float4 x0 = *(const float4*)(Af);
            float4 x1 = *(const float4*)(Af + 4);
            af[kk][0] = (short)f2bf_bits(x0.x);
            af[kk][1] = (short)f2bf_bits(x0.y);
            af[kk][2] = (short)f2bf_bits(x0.z);
            af[kk][3] = (short)f2bf_bits(x0.w);
            af[kk][4] = (short)f2bf_bits(x1.x);
            af[kk][5] = (short)f2bf_bits(x1.y);
            af[kk][6] = (short)f2bf_bits(x1.z);
            af[kk][7] = (short)f2bf_bits(x1.w);
        } else {
            af[kk] = *(const bf16x8*)((const unsigned short*)A + (size_t)ar_c * D + k);
        }
    }

#pragma unroll
    for (int i = 0; i < 4; i++)
        *(bf16x8*)(&Wt[0][(size_t)(tid + i * 512) * 8]) = wq[i];
#pragma unroll
    for (int i = 0; i < 4; i++)
        *(bf16x8*)(&Wt[1][(size_t)(tid + i * 512) * 8]) = wt[i];

    f32x4 accQ[8], accT[8];
#pragma unroll
    for (int i = 0; i < 8; i++) {
        accQ[i] = (f32x4){0.f, 0.f, 0.f, 0.f};
        accT[i] = (f32x4){0.f, 0.f, 0.f, 0.f};
    }

    __syncthreads();  // the ONLY barrier

#pragma unroll
    for (int nt = 0; nt < 8; nt++) {
#pragma unroll
        for (int kk = 0; kk < 4; kk++) {
            bf16x8 bq = *(const bf16x8*)(&Wt[0][(size_t)((nt * 4 + kk) * 64 + lane) * 8]);
            accQ[nt] = __builtin_amdgcn_mfma_f32_16x16x32_bf16(af[kk], bq, accQ[nt], 0, 0, 0);
        }
    }
#pragma unroll
    for (int nt = 0; nt < 8; nt++) {
#pragma unroll
        for (int kk = 0; kk < 4; kk++) {
            bf16x8 bt = *(const bf16x8*)(&Wt[1][(size_t)((nt * 4 + kk) * 64 + lane) * 8]);
            accT[nt] = __builtin_amdgcn_mfma_f32_16x16x32_bf16(af[kk], bt, accT[nt], 0, 0, 0);
        }
    }

    int cr0 = row0 + wv * 16 + quad * 4;
    int odd = l16 & 1;
    if (jp != 2) {
#pragma unroll
        for (int r = 0; r < 4; r++) {
            int cr = cr0 + r;
#pragma unroll
            for (int nt = 0; nt < 8; nt++) {
                float vQ = accQ[nt][r] * LOG2E;  // pre-scale logits for exp2
                float vT = accT[nt][r];
                float oQ = __shfl_xor(vQ, 1);
                float oT = __shfl_xor(vT, 1);
                unsigned w;
                if (!odd) w = (unsigned)f2bf_bits(vQ) | ((unsigned)f2bf_bits(oQ) << 16);
                else      w = (unsigned)f2bf_bits(oT) | ((unsigned)f2bf_bits(vT) << 16);
                if (cr < rows) O[(size_t)cr * 128 + nt * 16 + l16] = w;
            }
        }
    } else {
#pragma unroll
        for (int r = 0; r < 4; r++) {
            int cr = cr0 + r;
            int deg = (cr < rows) ? cnt[cr] : 0;
#pragma unroll
            for (int nt = 0; nt < 8; nt++) {
                float vL = accQ[nt][r], vE = accT[nt][r];
                float oL = __shfl_xor(vL, 1);
                float oE = __shfl_xor(vE, 1);
                unsigned wl, we;
                if (!odd) {
                    wl = (unsigned)f2bf_bits(vL) | ((unsigned)f2bf_bits(oL) << 16);
                    we = (unsigned)f2bf_bits(vE) | ((unsigned)f2bf_bits(oE) << 16);
                } else {
                    wl = (unsigned)f2bf_bits(oL) | ((unsigned)f2bf_bits(vL) << 16);
                    we = (unsigned)f2bf_bits(oE) | ((unsigned)f2bf_bits(vE) << 16);
                }
                if (cr < rows && !odd)
                    loopSel[(size_t)cr * 64 + nt * 8 + (l16 >> 1)] = (deg > 0) ? wl : we;
            }
        }
    }
}

// ---- K5: wave-per-node aggregation + layernorm. Best measured structure
// (R3/R5/R8/R11): single dispatch, compiler-pipelined gathers, forced v_pk
// math, raw v_exp_f32, pre-scaled byte-offset packets.
__global__ __launch_bounds__(256) void agg_kernel(
    const int* __restrict__ offs, const u32x2* __restrict__ ePack,
    const unsigned* __restrict__ ST, const unsigned* __restrict__ RT,
    const unsigned* __restrict__ DT, const unsigned* __restrict__ loopSel,
    const void* __restrict__ normv, void* __restrict__ out,
    const int* __restrict__ flag, int N) {
    int n = blockIdx.x * 4 + threadIdx.y;
    if (n >= N) return;
    int f32 = *flag;
    int lane = threadIdx.x;
    int half = lane >> 5, sl = lane & 31;
    int start = offs[n], end = offs[n + 1];
    int deg = end - start;

    u32x4 ud = *(const u32x4*)(DT + (size_t)n * 128 + sl * 4);
    f32x2 qd01 = unpk2(ud.x), td01 = unpk2(ud.y);
    f32x2 qd23 = unpk2(ud.z), td23 = unpk2(ud.w);
    u32x2 ul = *(const u32x2*)(loopSel + (size_t)n * 64 + sl * 2);
    f32x2 acc01 = unpk2(ul.x), acc23 = unpk2(ul.y);

    const char* STb = (const char*)ST;
    const char* RTb = (const char*)RT;
    unsigned laneoff = (unsigned)(sl * 16);

    f32x2 den01 = {0.f, 0.f}, den23 = {0.f, 0.f};
    f32x2 h01 = {0.f, 0.f}, h23 = {0.f, 0.f};
    const f32x2 ns2 = {0.01f, 0.01f};

#define GLOAD(PK, US, UR)                                                   \
    u32x4 US = *(const u32x4*)(STb + (size_t)((PK).x + laneoff));           \
    u32x4 UR = *(const u32x4*)(RTb + (size_t)((PK).y + laneoff));

#define EMATH(US, UR)                                                       \
    {                                                                       \
        f32x2 q01 = pk_add(pk_add(unpk2(US.x), unpk2(UR.x)), qd01);         \
        f32x2 q23 = pk_add(pk_add(unpk2(US.z), unpk2(UR.z)), qd23);         \
        f32x2 s01 = pk_mul(q01, ns2);                                       \
        f32x2 s23 = pk_mul(q23, ns2);                                       \
        f32x2 ex01, ex23;                                                   \
        ex01.x = fexp2(fmaxf(q01.x, s01.x));                                \
        ex01.y = fexp2(fmaxf(q01.y, s01.y));                                \
        ex23.x = fexp2(fmaxf(q23.x, s23.x));                                \
        ex23.y = fexp2(fmaxf(q23.y, s23.y));                                \
        den01 = pk_add(den01, ex01); den23 = pk_add(den23, ex23);           \
        f32x2 t01 = pk_add(pk_add(unpk2(US.y), unpk2(UR.y)), td01);         \
        f32x2 t23 = pk_add(pk_add(unpk2(US.w), unpk2(UR.w)), td23);         \
        h01 = pk_fma(ex01, t01, h01);                                       \
        h23 = pk_fma(ex23, t23, h23);                                       \
    }

#define EMATHV(US, UR, VM)                                                  \
    {                                                                       \
        f32x2 q01 = pk_add(pk_add(unpk2(US.x), unpk2(UR.x)), qd01);         \
        f32x2 q23 = pk_add(pk_add(unpk2(US.z), unpk2(UR.z)), qd23);         \
        f32x2 s01 = pk_mul(q01, ns2);                                       \
        f32x2 s23 = pk_mul(q23, ns2);                                       \
        f32x2 ex01, ex23;                                                   \
        ex01.x = fexp2(fmaxf(q01.x, s01.x)) * (VM);                         \
        ex01.y = fexp2(fmaxf(q01.y, s01.y)) * (VM);                         \
        ex23.x = fexp2(fmaxf(q23.x, s23.x)) * (VM);                         \
        ex23.y = fexp2(fmaxf(q23.y, s23.y)) * (VM);                         \
        den01 = pk_add(den01, ex01); den23 = pk_add(den23, ex23);           \
        f32x2 t01 = pk_add(pk_add(unpk2(US.y), unpk2(UR.y)), td01);         \
        f32x2 t23 = pk_add(pk_add(unpk2(US.w), unpk2(UR.w)), td23);         \
        h01 = pk_fma(ex01, t01, h01);                                       \
        h23 = pk_fma(ex23, t23, h23);                                       \
    }

    int e = start;
    for (; e + 3 < end; e += 4) {
        u32x2 pA = ePack[e + half];
        u32x2 pB = ePack[e + 2 + half];
        GLOAD(pA, usA, urA)
        GLOAD(pB, usB, urB)
        EMATH(usA, urA)
        EMATH(usB, urB)
    }
    for (; e < end; e += 2) {
        int eh = e + half;
        int valid = eh < end;
        u32x2 pT = ePack[valid ? eh : end - 1];
        GLOAD(pT, usT, urT)
        EMATHV(usT, urT, valid ? 1.0f : 0.0f)
    }
#undef GLOAD
#undef EMATH
#undef EMATHV

    // merge the two edge-subsets (lane l <-> l+32 hold same channels)
    den01 = pk_add(den01, shx32(den01)); den23 = pk_add(den23, shx32(den23));
    h01 = pk_add(h01, shx32(h01));       h23 = pk_add(h23, shx32(h23));

    f32x2 x01, x23;
    if (deg > 0) {
        float nrm = ldf(normv, n, f32);
        x01 = h01 / den01 * nrm + acc01;
        x23 = h23 / den23 * nrm + acc23;
    } else {
        x01 = acc01;
        x23 = acc23;
    }

    // halves identical: 5-step butterfly over 32 lanes x 4 ch = 128
    float s = (x01.x + x01.y) + (x23.x + x23.y);
    float ss = (x01.x * x01.x + x01.y * x01.y) + (x23.x * x23.x + x23.y * x23.y);
#pragma unroll
    for (int o = 16; o; o >>= 1) {
        s += __shfl_xor(s, o);
        ss += __shfl_xor(ss, o);
    }
    float mu = s * (1.f / 128.f);
    float var = ss * (1.f / 128.f) - mu * mu;
    float rstd = rsqrtf(var + 1e-5f);
    f32x2 y01 = (x01 - mu) * rstd;
    f32x2 y23 = (x23 - mu) * rstd;

    if (half == 0) {
        if (f32) {
            float4 o4 = make_float4(y01.x, y01.y, y23.x, y23.y);
            ((float4*)out)[(size_t)n * 32 + sl] = o4;
        } else {
            u32x2 ow;
            ow.x = (unsigned)f2bf_bits(y01.x) | ((unsigned)f2bf_bits(y01.y) << 16);
            ow.y = (unsigned)f2bf_bits(y23.x) | ((unsigned)f2bf_bits(y23.y) << 16);
            *(u32x2*)((unsigned*)out + (size_t)n * 64 + sl * 2) = ow;
        }
    }
}

extern "C" void kernel_launch(void* const* d_in, const int* in_sizes, int n_in,
                              void* d_out, int out_size, void* d_ws, size_t ws_size,
                              hipStream_t stream) {
    const void* node = d_in[0];
    const void* rel = d_in[1];
    const void* normv = d_in[2];
    const void* wtrip = d_in[3];
    const void* wquad = d_in[4];
    const void* loopW = d_in[5];
    const void* evoW = d_in[6];
    const int* src = (const int*)d_in[7];
    const int* dst = (const int*)d_in[8];
    const int* et = (const int*)d_in[9];

    int N = in_sizes[0] / D;
    int R = in_sizes[1] / D;
    int E = in_sizes[7];
    int nb = (N + 255) / 256;       // 196 scan blocks (<= 256 required)
    int nodeBlocks = (N + 127) / 128;
    int relBlocks = (R + 127) / 128;
    int scatBlocks = (E + 511) / 512;

    char* p = (char*)d_ws;
    auto alloc = [&](size_t bytes) -> void* {
        void* r = (void*)p;
        p += (bytes + 255) & ~(size_t)255;
        return r;
    };
    unsigned* nodeST = (unsigned*)alloc((size_t)N * 128 * 4);
    unsigned* nodeDT = (unsigned*)alloc((size_t)N * 128 * 4);
    unsigned* relRT = (unsigned*)alloc((size_t)R * 128 * 4);
    unsigned* loopSel = (unsigned*)alloc((size_t)N * 64 * 4);
    unsigned short* wT = (unsigned short*)alloc((size_t)8 * D * D * 2);
    int* cnt = (int*)alloc((size_t)N * 4);
    int* offs = (int*)alloc((size_t)(N + 1) * 4);
    int* part = (int*)alloc((size_t)(nb + 1) * 4);
    int* rank = (int*)alloc((size_t)E * 4);
    u32x2* ePack = (u32x2*)alloc((size_t)E * 8);
    int* flag = (int*)alloc(4);
    int* bar = (int*)alloc(64);

    // 4 dispatches total (was 6): tiny memset (barrier counters), fused
    // prep (weights || zero+count+rank+scan via software grid barrier),
    // gemm, agg.
    hipMemsetAsync(bar, 0, 64, stream);
    prep_kernel<<<nb + 272, 256, 0, stream>>>(
        node, wtrip, wquad, loopW, evoW, wT, cnt, offs, part, rank, dst,
        flag, bar, E, N, nb);
    int xext = nodeBlocks + (scatBlocks > relBlocks ? scatBlocks : relBlocks);
    gemm_kernel<<<dim3(xext, 3), dim3(64, 8), 0, stream>>>(
        node, rel, wT, cnt, nodeST, nodeDT, relRT, loopSel, flag, N, R, nodeBlocks,
        src, dst, et, offs, rank, ePack, E);
    agg_kernel<<<(N + 3) / 4, dim3(64, 4), 0, stream>>>(
        offs, ePack, nodeST, relRT, nodeDT, loopSel, normv, d_out, flag, N);
}

// Round 13
// 224.234 us; speedup vs baseline: 1.1337x; 1.1337x over previous
//
#include <hip/hip_runtime.h>
#include <hip/hip_bf16.h>

#define D 128
#define LOG2E 1.4426950408889634f

typedef __attribute__((ext_vector_type(8))) short bf16x8;
typedef __attribute__((ext_vector_type(4))) float f32x4;
typedef __attribute__((ext_vector_type(2))) float f32x2;
typedef __attribute__((ext_vector_type(2))) unsigned u32x2;
typedef __attribute__((ext_vector_type(4))) unsigned u32x4;

__device__ __forceinline__ unsigned short f2bf_bits(float f) {
    union { __hip_bfloat16 h; unsigned short u; } c;
    c.h = __float2bfloat16(f);
    return c.u;
}
__device__ __forceinline__ float bfbits2f(unsigned short u) {
    return __uint_as_float(((unsigned)u) << 16);
}
__device__ __forceinline__ float ldf(const void* p, size_t i, int f32) {
    return f32 ? ((const float*)p)[i] : bfbits2f(((const unsigned short*)p)[i]);
}
// word -> (lo bf16, hi bf16) as packed f32 pair
__device__ __forceinline__ f32x2 unpk2(unsigned u) {
    f32x2 r;
    r.x = __uint_as_float(u << 16);
    r.y = __uint_as_float(u & 0xFFFF0000u);
    return r;
}
__device__ __forceinline__ f32x2 shx32(f32x2 v) {
    f32x2 r;
    r.x = __shfl_xor(v.x, 32);
    r.y = __shfl_xor(v.y, 32);
    return r;
}
// Forced packed-fp32 math (backend does not reliably select these from IR)
__device__ __forceinline__ f32x2 pk_add(f32x2 a, f32x2 b) {
    f32x2 d;
    asm("v_pk_add_f32 %0, %1, %2" : "=v"(d) : "v"(a), "v"(b));
    return d;
}
__device__ __forceinline__ f32x2 pk_mul(f32x2 a, f32x2 b) {
    f32x2 d;
    asm("v_pk_mul_f32 %0, %1, %2" : "=v"(d) : "v"(a), "v"(b));
    return d;
}
__device__ __forceinline__ f32x2 pk_fma(f32x2 a, f32x2 b, f32x2 c) {
    f32x2 d;
    asm("v_pk_fma_f32 %0, %1, %2, %3" : "=v"(d) : "v"(a), "v"(b), "v"(c));
    return d;
}
__device__ __forceinline__ float fexp2(float x) {  // raw v_exp_f32 (2^x)
    float r;
    asm("v_exp_f32 %0, %1" : "=v"(r) : "v"(x));
    return r;
}

// Fragment-major W layout: 16B-unit index for element (row, k):
//   f16 = ((row>>4)*4 + (k>>5))*64 + ((k>>3)&3)*16 + (row&15)
// gemm's MFMA fragment (nt,kk,lane) sits at unit (nt*4+kk)*64 + lane —
// sequential across lanes => coalesced staging + conflict-free LDS reads.
__device__ __forceinline__ size_t fragIdx(int row, int k) {
    int f16 = ((row >> 4) * 4 + (k >> 5)) * 64 + ((k >> 3) & 3) * 16 + (row & 15);
    return (size_t)f16 * 8 + (k & 7);
}

// ---- K1: prep = dtype-detect (per-block local) + wq (transposed write)
//         + trans of 5 raw weights + count (rank captured for free).
// wT job map: 0 Wsq_s 1 W_s 2 Wsq_d 3 W_d 4 loopW 5 evoW 6 Wsq_r 7 W_r
// All tables stored FRAGMENT-MAJOR (see fragIdx).
__global__ __launch_bounds__(256) void prep_kernel(
    const void* __restrict__ node, const void* __restrict__ wtrip,
    const void* __restrict__ wquad, const void* __restrict__ loopW,
    const void* __restrict__ evoW, unsigned short* __restrict__ wT,
    int* __restrict__ cnt, int* __restrict__ rank,
    const int* __restrict__ dst, int* __restrict__ flag, int E) {
    __shared__ int sflag;
    int tid = threadIdx.x;
    int bad = 0;
    if (tid < 64) {
        for (int j = 0; j < 4; j++) {
            float v = bfbits2f(((const unsigned short*)node)[tid + 64 * j]);
            if (!(fabsf(v) < 1e4f)) bad = 1;
        }
    }
    unsigned long long m = __ballot(bad);
    if (tid == 0) sflag = (m != 0ull) ? 1 : 0;
    __syncthreads();
    int f32 = sflag;
    int bx = blockIdx.x;
    if (bx == 0 && tid == 0) *flag = f32;

    if (bx < 192) {
        int unit = bx * 2 + (tid >> 7);
        int k = unit & 127, mjob = unit >> 7;
        int t = tid & 127;
        float acc = 0.f;
        for (int j = 0; j < D; j++)
            acc += ldf(wtrip, (size_t)mjob * D * D + (size_t)k * D + j, f32) *
                   ldf(wquad, (size_t)j * D + t, f32);
        const int jmap0 = (mjob == 0) ? 0 : (mjob == 1 ? 6 : 2);
        wT[(size_t)jmap0 * D * D + fragIdx(t, k)] = f2bf_bits(acc);
    } else if (bx < 272) {
        int u = bx - 192;   // [0,80): 5 jobs x 16 segments
        int jr = u >> 4, seg = u & 15;
        const void* srcp; size_t base; int j;
        switch (jr) {
            case 0: srcp = wtrip; base = 0;             j = 1; break;
            case 1: srcp = wtrip; base = 2 * D * D;     j = 3; break;
            case 2: srcp = loopW; base = 0;             j = 4; break;
            case 3: srcp = evoW;  base = 0;             j = 5; break;
            default: srcp = wtrip; base = (size_t)D * D; j = 7; break;
        }
        for (int c = tid; c < 1024; c += 256) {
            int idx = seg * 1024 + c;
            int n = idx >> 7, k = idx & 127;
            unsigned short b = f32 ? f2bf_bits(((const float*)srcp)[base + (size_t)k * D + n])
                                   : ((const unsigned short*)srcp)[base + (size_t)k * D + n];
            wT[(size_t)j * D * D + fragIdx(n, k)] = b;
        }
    } else {
        int e = (bx - 272) * 256 + tid;
        if (e < E) rank[e] = atomicAdd(&cnt[dst[e]], 1);
    }
}

// ---- K2: per-block exclusive scan, block totals to part ----
__global__ void scan_block(const int* __restrict__ cnt, int* __restrict__ offs,
                           int* __restrict__ part, int N) {
    __shared__ int sh[256];
    int tid = threadIdx.x;
    int i = blockIdx.x * 256 + tid;
    int v = (i < N) ? cnt[i] : 0;
    sh[tid] = v;
    __syncthreads();
    for (int o = 1; o < 256; o <<= 1) {
        int t = (tid >= o) ? sh[tid - o] : 0;
        __syncthreads();
        sh[tid] += t;
        __syncthreads();
    }
    if (i < N) offs[i] = sh[tid] - v;
    if (tid == 255) part[blockIdx.x] = sh[255];
}

// ---- K3: each block reduces part[0..b) itself, adds carry (nb<=256) ----
__global__ void scan_fix(int* __restrict__ offs, const int* __restrict__ part,
                         int N, int E) {
    __shared__ int sh[256];
    int tid = threadIdx.x, b = blockIdx.x;
    sh[tid] = (tid < b) ? part[tid] : 0;
    __syncthreads();
    for (int o = 128; o; o >>= 1) {
        if (tid < o) sh[tid] += sh[tid + o];
        __syncthreads();
    }
    int carry = sh[0];
    int i = b * 256 + tid;
    if (i < N) offs[i] += carry;
    if (b == 0 && tid == 0) offs[N] = E;
}

// ---- K4: table GEMM, single barrier: both W tables (64KB total,
// fragment-major) staged into LDS up-front with 8 coalesced loads in
// flight, ONE __syncthreads, then all 64 MFMA as an uninterrupted cluster.
// LDS 64KB -> 2 blocks/CU. Scatter fused at y==1 x-overflow.
__global__ __launch_bounds__(512) void gemm_kernel(
    const void* __restrict__ node, const void* __restrict__ rel,
    const unsigned short* __restrict__ wT, const int* __restrict__ cnt,
    unsigned* __restrict__ nodeST, unsigned* __restrict__ nodeDT,
    unsigned* __restrict__ relRT, unsigned* __restrict__ loopSel,
    const int* __restrict__ flag, int N, int R, int nodeBlocks,
    const int* __restrict__ src, const int* __restrict__ dst,
    const int* __restrict__ et, const int* __restrict__ offs,
    const int* __restrict__ rank, u32x2* __restrict__ ePack, int E) {
    __shared__ __align__(16) unsigned short Wt[2][D * D];  // 2 x 32KB, fragment-major

    int bx = blockIdx.x, by = blockIdx.y;
    int tid = threadIdx.y * 64 + threadIdx.x;
    int isRel = 0, jp;
    if (bx >= nodeBlocks) {
        if (by == 1) {  // scatter range: pure (no atomics)
            int e = (bx - nodeBlocks) * 512 + tid;
            if (e < E) {
                int d = dst[e];
                u32x2 pk;
                pk.x = ((unsigned)src[e]) << 9;
                pk.y = ((unsigned)et[e]) << 9;
                ePack[offs[d] + rank[e]] = pk;
            }
            return;
        }
        if (by != 0 || bx - nodeBlocks >= (R + 127) / 128) return;
        isRel = 1;
        jp = 3;
    } else {
        jp = by;
    }

    int f32 = *flag;
    int rows = isRel ? R : N;
    int row0 = (isRel ? bx - nodeBlocks : bx) * 128;
    const void* A = isRel ? rel : node;

    int lane = threadIdx.x, wv = threadIdx.y;  // wv in [0,8)
    int l16 = lane & 15, quad = lane >> 4;
    int ar = row0 + wv * 16 + l16;
    int ar_c = ar < rows ? ar : rows - 1;

    int qIdx, tIdx;
    unsigned* O = nullptr;
    switch (jp) {
        case 0: qIdx = 0; tIdx = 1; O = nodeST; break;
        case 1: qIdx = 2; tIdx = 3; O = nodeDT; break;
        case 2: qIdx = 4; tIdx = 5; break;  // loopW/evoW pair
        default: qIdx = 6; tIdx = 7; O = relRT; break;
    }

    const unsigned short* gQ = wT + (size_t)qIdx * D * D;
    const unsigned short* gT = wT + (size_t)tIdx * D * D;

    // stage BOTH tables: 8 independent coalesced 16B loads issued together
    bf16x8 wq[4], wt[4];
#pragma unroll
    for (int i = 0; i < 4; i++)
        wq[i] = *(const bf16x8*)(gQ + (size_t)(tid + i * 512) * 8);
#pragma unroll
    for (int i = 0; i < 4; i++)
        wt[i] = *(const bf16x8*)(gT + (size_t)(tid + i * 512) * 8);

    bf16x8 af[4];
#pragma unroll
    for (int kk = 0; kk < 4; kk++) {
        int k = kk * 32 + quad * 8;
        if (f32) {
            const float* Af = (const float*)A + (size_t)ar_c * D + k;
            float4 x0 = *(const float4*)(Af);
            float4 x1 = *(const float4*)(Af + 4);
            af[kk][0] = (short)f2bf_bits(x0.x);
            af[kk][1] = (short)f2bf_bits(x0.y);
            af[kk][2] = (short)f2bf_bits(x0.z);
            af[kk][3] = (short)f2bf_bits(x0.w);
            af[kk][4] = (short)f2bf_bits(x1.x);
            af[kk][5] = (short)f2bf_bits(x1.y);
            af[kk][6] = (short)f2bf_bits(x1.z);
            af[kk][7] = (short)f2bf_bits(x1.w);
        } else {
            af[kk] = *(const bf16x8*)((const unsigned short*)A + (size_t)ar_c * D + k);
        }
    }

#pragma unroll
    for (int i = 0; i < 4; i++)  // linear LDS writes: zero conflicts
        *(bf16x8*)(&Wt[0][(size_t)(tid + i * 512) * 8]) = wq[i];
#pragma unroll
    for (int i = 0; i < 4; i++)
        *(bf16x8*)(&Wt[1][(size_t)(tid + i * 512) * 8]) = wt[i];

    f32x4 accQ[8], accT[8];
#pragma unroll
    for (int i = 0; i < 8; i++) {
        accQ[i] = (f32x4){0.f, 0.f, 0.f, 0.f};
        accT[i] = (f32x4){0.f, 0.f, 0.f, 0.f};
    }

    __syncthreads();  // the ONLY barrier

#pragma unroll
    for (int nt = 0; nt < 8; nt++) {
#pragma unroll
        for (int kk = 0; kk < 4; kk++) {
            bf16x8 bq = *(const bf16x8*)(&Wt[0][(size_t)((nt * 4 + kk) * 64 + lane) * 8]);
            accQ[nt] = __builtin_amdgcn_mfma_f32_16x16x32_bf16(af[kk], bq, accQ[nt], 0, 0, 0);
        }
    }
#pragma unroll
    for (int nt = 0; nt < 8; nt++) {
#pragma unroll
        for (int kk = 0; kk < 4; kk++) {
            bf16x8 bt = *(const bf16x8*)(&Wt[1][(size_t)((nt * 4 + kk) * 64 + lane) * 8]);
            accT[nt] = __builtin_amdgcn_mfma_f32_16x16x32_bf16(af[kk], bt, accT[nt], 0, 0, 0);
        }
    }

    int cr0 = row0 + wv * 16 + quad * 4;
    int odd = l16 & 1;
    if (jp != 2) {
#pragma unroll
        for (int r = 0; r < 4; r++) {
            int cr = cr0 + r;
#pragma unroll
            for (int nt = 0; nt < 8; nt++) {
                float vQ = accQ[nt][r] * LOG2E;  // pre-scale logits for exp2
                float vT = accT[nt][r];
                float oQ = __shfl_xor(vQ, 1);
                float oT = __shfl_xor(vT, 1);
                unsigned w;
                if (!odd) w = (unsigned)f2bf_bits(vQ) | ((unsigned)f2bf_bits(oQ) << 16);
                else      w = (unsigned)f2bf_bits(oT) | ((unsigned)f2bf_bits(vT) << 16);
                if (cr < rows) O[(size_t)cr * 128 + nt * 16 + l16] = w;
            }
        }
    } else {
#pragma unroll
        for (int r = 0; r < 4; r++) {
            int cr = cr0 + r;
            int deg = (cr < rows) ? cnt[cr] : 0;
#pragma unroll
            for (int nt = 0; nt < 8; nt++) {
                float vL = accQ[nt][r], vE = accT[nt][r];
                float oL = __shfl_xor(vL, 1);
                float oE = __shfl_xor(vE, 1);
                unsigned wl, we;
                if (!odd) {
                    wl = (unsigned)f2bf_bits(vL) | ((unsigned)f2bf_bits(oL) << 16);
                    we = (unsigned)f2bf_bits(vE) | ((unsigned)f2bf_bits(oE) << 16);
                } else {
                    wl = (unsigned)f2bf_bits(oL) | ((unsigned)f2bf_bits(vL) << 16);
                    we = (unsigned)f2bf_bits(oE) | ((unsigned)f2bf_bits(vE) << 16);
                }
                if (cr < rows && !odd)
                    loopSel[(size_t)cr * 64 + nt * 8 + (l16 >> 1)] = (deg > 0) ? wl : we;
            }
        }
    }
}

// ---- K5: wave-per-node aggregation + layernorm. Best measured structure
// (R3/R5/R8/R11): single dispatch, compiler-pipelined gathers, forced v_pk
// math, raw v_exp_f32, pre-scaled byte-offset packets.
__global__ __launch_bounds__(256) void agg_kernel(
    const int* __restrict__ offs, const u32x2* __restrict__ ePack,
    const unsigned* __restrict__ ST, const unsigned* __restrict__ RT,
    const unsigned* __restrict__ DT, const unsigned* __restrict__ loopSel,
    const void* __restrict__ normv, void* __restrict__ out,
    const int* __restrict__ flag, int N) {
    int n = blockIdx.x * 4 + threadIdx.y;
    if (n >= N) return;
    int f32 = *flag;
    int lane = threadIdx.x;
    int half = lane >> 5, sl = lane & 31;
    int start = offs[n], end = offs[n + 1];
    int deg = end - start;

    u32x4 ud = *(const u32x4*)(DT + (size_t)n * 128 + sl * 4);
    f32x2 qd01 = unpk2(ud.x), td01 = unpk2(ud.y);
    f32x2 qd23 = unpk2(ud.z), td23 = unpk2(ud.w);
    u32x2 ul = *(const u32x2*)(loopSel + (size_t)n * 64 + sl * 2);
    f32x2 acc01 = unpk2(ul.x), acc23 = unpk2(ul.y);

    const char* STb = (const char*)ST;
    const char* RTb = (const char*)RT;
    unsigned laneoff = (unsigned)(sl * 16);

    f32x2 den01 = {0.f, 0.f}, den23 = {0.f, 0.f};
    f32x2 h01 = {0.f, 0.f}, h23 = {0.f, 0.f};
    const f32x2 ns2 = {0.01f, 0.01f};

#define GLOAD(PK, US, UR)                                                   \
    u32x4 US = *(const u32x4*)(STb + (size_t)((PK).x + laneoff));           \
    u32x4 UR = *(const u32x4*)(RTb + (size_t)((PK).y + laneoff));

#define EMATH(US, UR)                                                       \
    {                                                                       \
        f32x2 q01 = pk_add(pk_add(unpk2(US.x), unpk2(UR.x)), qd01);         \
        f32x2 q23 = pk_add(pk_add(unpk2(US.z), unpk2(UR.z)), qd23);         \
        f32x2 s01 = pk_mul(q01, ns2);                                       \
        f32x2 s23 = pk_mul(q23, ns2);                                       \
        f32x2 ex01, ex23;                                                   \
        ex01.x = fexp2(fmaxf(q01.x, s01.x));                                \
        ex01.y = fexp2(fmaxf(q01.y, s01.y));                                \
        ex23.x = fexp2(fmaxf(q23.x, s23.x));                                \
        ex23.y = fexp2(fmaxf(q23.y, s23.y));                                \
        den01 = pk_add(den01, ex01); den23 = pk_add(den23, ex23);           \
        f32x2 t01 = pk_add(pk_add(unpk2(US.y), unpk2(UR.y)), td01);         \
        f32x2 t23 = pk_add(pk_add(unpk2(US.w), unpk2(UR.w)), td23);         \
        h01 = pk_fma(ex01, t01, h01);                                       \
        h23 = pk_fma(ex23, t23, h23);                                       \
    }

#define EMATHV(US, UR, VM)                                                  \
    {                                                                       \
        f32x2 q01 = pk_add(pk_add(unpk2(US.x), unpk2(UR.x)), qd01);         \
        f32x2 q23 = pk_add(pk_add(unpk2(US.z), unpk2(UR.z)), qd23);         \
        f32x2 s01 = pk_mul(q01, ns2);                                       \
        f32x2 s23 = pk_mul(q23, ns2);                                       \
        f32x2 ex01, ex23;                                                   \
        ex01.x = fexp2(fmaxf(q01.x, s01.x)) * (VM);                         \
        ex01.y = fexp2(fmaxf(q01.y, s01.y)) * (VM);                         \
        ex23.x = fexp2(fmaxf(q23.x, s23.x)) * (VM);                         \
        ex23.y = fexp2(fmaxf(q23.y, s23.y)) * (VM);                         \
        den01 = pk_add(den01, ex01); den23 = pk_add(den23, ex23);           \
        f32x2 t01 = pk_add(pk_add(unpk2(US.y), unpk2(UR.y)), td01);         \
        f32x2 t23 = pk_add(pk_add(unpk2(US.w), unpk2(UR.w)), td23);         \
        h01 = pk_fma(ex01, t01, h01);                                       \
        h23 = pk_fma(ex23, t23, h23);                                       \
    }

    int e = start;
    for (; e + 3 < end; e += 4) {
        u32x2 pA = ePack[e + half];
        u32x2 pB = ePack[e + 2 + half];
        GLOAD(pA, usA, urA)
        GLOAD(pB, usB, urB)
        EMATH(usA, urA)
        EMATH(usB, urB)
    }
    for (; e < end; e += 2) {
        int eh = e + half;
        int valid = eh < end;
        u32x2 pT = ePack[valid ? eh : end - 1];
        GLOAD(pT, usT, urT)
        EMATHV(usT, urT, valid ? 1.0f : 0.0f)
    }
#undef GLOAD
#undef EMATH
#undef EMATHV

    // merge the two edge-subsets (lane l <-> l+32 hold same channels)
    den01 = pk_add(den01, shx32(den01)); den23 = pk_add(den23, shx32(den23));
    h01 = pk_add(h01, shx32(h01));       h23 = pk_add(h23, shx32(h23));

    f32x2 x01, x23;
    if (deg > 0) {
        float nrm = ldf(normv, n, f32);
        x01 = h01 / den01 * nrm + acc01;
        x23 = h23 / den23 * nrm + acc23;
    } else {
        x01 = acc01;
        x23 = acc23;
    }

    // halves identical: 5-step butterfly over 32 lanes x 4 ch = 128
    float s = (x01.x + x01.y) + (x23.x + x23.y);
    float ss = (x01.x * x01.x + x01.y * x01.y) + (x23.x * x23.x + x23.y * x23.y);
#pragma unroll
    for (int o = 16; o; o >>= 1) {
        s += __shfl_xor(s, o);
        ss += __shfl_xor(ss, o);
    }
    float mu = s * (1.f / 128.f);
    float var = ss * (1.f / 128.f) - mu * mu;
    float rstd = rsqrtf(var + 1e-5f);
    f32x2 y01 = (x01 - mu) * rstd;
    f32x2 y23 = (x23 - mu) * rstd;

    if (half == 0) {
        if (f32) {
            float4 o4 = make_float4(y01.x, y01.y, y23.x, y23.y);
            ((float4*)out)[(size_t)n * 32 + sl] = o4;
        } else {
            u32x2 ow;
            ow.x = (unsigned)f2bf_bits(y01.x) | ((unsigned)f2bf_bits(y01.y) << 16);
            ow.y = (unsigned)f2bf_bits(y23.x) | ((unsigned)f2bf_bits(y23.y) << 16);
            *(u32x2*)((unsigned*)out + (size_t)n * 64 + sl * 2) = ow;
        }
    }
}

extern "C" void kernel_launch(void* const* d_in, const int* in_sizes, int n_in,
                              void* d_out, int out_size, void* d_ws, size_t ws_size,
                              hipStream_t stream) {
    const void* node = d_in[0];
    const void* rel = d_in[1];
    const void* normv = d_in[2];
    const void* wtrip = d_in[3];
    const void* wquad = d_in[4];
    const void* loopW = d_in[5];
    const void* evoW = d_in[6];
    const int* src = (const int*)d_in[7];
    const int* dst = (const int*)d_in[8];
    const int* et = (const int*)d_in[9];

    int N = in_sizes[0] / D;
    int R = in_sizes[1] / D;
    int E = in_sizes[7];
    int nb = (N + 255) / 256;
    int nodeBlocks = (N + 127) / 128;
    int relBlocks = (R + 127) / 128;
    int scatBlocks = (E + 511) / 512;

    char* p = (char*)d_ws;
    auto alloc = [&](size_t bytes) -> void* {
        void* r = (void*)p;
        p += (bytes + 255) & ~(size_t)255;
        return r;
    };
    unsigned* nodeST = (unsigned*)alloc((size_t)N * 128 * 4);
    unsigned* nodeDT = (unsigned*)alloc((size_t)N * 128 * 4);
    unsigned* relRT = (unsigned*)alloc((size_t)R * 128 * 4);
    unsigned* loopSel = (unsigned*)alloc((size_t)N * 64 * 4);
    unsigned short* wT = (unsigned short*)alloc((size_t)8 * D * D * 2);
    int* cnt = (int*)alloc((size_t)N * 4);
    int* offs = (int*)alloc((size_t)(N + 1) * 4);
    int* part = (int*)alloc((size_t)(nb + 1) * 4);
    int* rank = (int*)alloc((size_t)E * 4);
    u32x2* ePack = (u32x2*)alloc((size_t)E * 8);
    int* flag = (int*)alloc(4);

    hipMemsetAsync(cnt, 0, (size_t)N * 4, stream);
    prep_kernel<<<272 + (E + 255) / 256, 256, 0, stream>>>(
        node, wtrip, wquad, loopW, evoW, wT, cnt, rank, dst, flag, E);
    scan_block<<<nb, 256, 0, stream>>>(cnt, offs, part, N);
    scan_fix<<<nb, 256, 0, stream>>>(offs, part, N, E);
    int xext = nodeBlocks + (scatBlocks > relBlocks ? scatBlocks : relBlocks);
    gemm_kernel<<<dim3(xext, 3), dim3(64, 8), 0, stream>>>(
        node, rel, wT, cnt, nodeST, nodeDT, relRT, loopSel, flag, N, R, nodeBlocks,
        src, dst, et, offs, rank, ePack, E);
    agg_kernel<<<(N + 3) / 4, dim3(64, 4), 0, stream>>>(
        offs, ePack, nodeST, relRT, nodeDT, loopSel, normv, d_out, flag, N);
}